// Round 7
// baseline (255.071 us; speedup 1.0000x reference)
//
#include <hip/hip_runtime.h>
#include <hip/hip_fp16.h>
#include <stdint.h>

// Problem constants (from reference setup_inputs)
#define BATCH 256
#define PSEL  128
#define IN_DIM 3200
#define O1_DIM 8192
#define O3_DIM 4096

// table sizes (halves)
#define XT_ELEMS  (IN_DIM * BATCH)    // 819,200 halves = 1,638,400 B
#define H_ELEMS   (O1_DIM * BATCH)    // 2,097,152 halves = 4,194,304 B

// ---------------------------------------------------------------------------
// transpose x [256, 3200] fp32 -> xT [3200, 256] fp16, written to 4 COPIES
// (consumers hash-select a copy; combined 6.4 MB footprint per XCD exceeds
//  the 4 MiB L2 so ~40% of gather lines are served by the parallel L3 path).
// Fused: out = -8.0 (final bias; atomics accumulate on top) and
// stats accumulators (4 x 256 floats) = 0.
// ---------------------------------------------------------------------------
__global__ __launch_bounds__(256) void transpose_kernel(const float* __restrict__ x,
                                                        __half* __restrict__ xT,
                                                        float* __restrict__ out,
                                                        float* __restrict__ stats) {
    int tx = threadIdx.x;       // 32
    int ty = threadIdx.y;       // 8
    int tid = ty * 32 + tx;
    int gid = blockIdx.y * gridDim.x + blockIdx.x;   // 0..799
    if (gid < 256) out[gid * 256 + tid] = -8.0f;
    else if (gid < 260) stats[(gid - 256) * 256 + tid] = 0.0f;

    __shared__ float tile[32][33];
    int i0 = blockIdx.x * 32;   // input-dim tile (3200/32 = 100)
    int b0 = blockIdx.y * 32;   // batch tile    (256/32 = 8)
#pragma unroll
    for (int k = 0; k < 4; ++k)
        tile[ty + k * 8][tx] = x[(size_t)(b0 + ty + k * 8) * IN_DIM + i0 + tx];
    __syncthreads();
#pragma unroll
    for (int k = 0; k < 4; ++k) {
        __half v = __float2half(tile[tx][ty + k * 8]);
        size_t off = (size_t)(i0 + ty + k * 8) * BATCH + b0 + tx;
#pragma unroll
        for (int c = 0; c < 4; ++c)
            xT[(size_t)c * XT_ELEMS + off] = v;
    }
}

// ---------------------------------------------------------------------------
// stats: per-batch-column sum and sum-of-squares of hT [N, 256] (fp16 in, fp32 acc)
// grid = 256 blocks, each handles N/256 contiguous rows; coalesced reads.
// ---------------------------------------------------------------------------
__global__ __launch_bounds__(256) void stats_kernel(const __half* __restrict__ hT,
                                                    float* __restrict__ gsum,
                                                    float* __restrict__ gsq,
                                                    int rows_per_block) {
    int t = threadIdx.x;
    const __half* p = hT + (size_t)blockIdx.x * rows_per_block * BATCH + t;
    float s = 0.0f, q = 0.0f;
    for (int r = 0; r < rows_per_block; ++r) {
        float v = __half2float(p[(size_t)r * BATCH]);
        s += v;
        q = fmaf(v, v, q);
    }
    atomicAdd(&gsum[t], s);
    atomicAdd(&gsq[t], q);
}

// ---------------------------------------------------------------------------
// popcnt layer (R5 structure, proven best): one block (256 threads) per
// output o. Thread t: batch-dword col = t&127, row-parity rp = t>>7; 64 thin
// dword loads per thread; halves combined via LDS at the end.
// NEW: gather base selects one of NCOPY table replicas by a hash of o that is
// decorrelated from the blockIdx%8 XCD mapping -> per-XCD requested footprint
// = NCOPY * table > 4 MiB L2 -> L3 serves ~half the lines in parallel.
// Layernorm of the INPUT folded algebraically:
//   sum_p w_p*((v-mu)*rs*g_p + be_p) = rs*acc + sumC - rs*mu*sumA
// Non-FINAL: stores the output row to BOTH h-table copies.
// FINAL: atomicAdd sigmoid into out[b*256 + o/16] (pre-init'd to -8).
// ---------------------------------------------------------------------------
template <bool NORM, bool FINAL, int CMASK>
__global__ __launch_bounds__(256) void popcnt_kernel(
    const __half* __restrict__ actT,  // [NCOPY][Nin, 256] fp16, rows = 512 B
    size_t copy_stride,               // elems per copy
    const int* __restrict__ sel,      // [Nout, 128]
    const float* __restrict__ w,      // [Nout, 128]
    const float* __restrict__ bias,   // [Nout]
    const float* __restrict__ g,      // [Nin]  (NORM only)
    const float* __restrict__ be,     // [Nin]  (NORM only)
    const float* __restrict__ gsum,   // [256]  (NORM only)
    const float* __restrict__ gsq,    // [256]  (NORM only)
    float inv_n,                      // 1/Nin  (NORM only)
    void* __restrict__ outp)          // fp16 2x[Nout,256] or final fp32 [256,256]
{
    const int o   = blockIdx.x;
    const int t   = threadIdx.x;      // 0..255
    const int col = t & 127;          // batch dword
    const int rp  = t >> 7;           // row parity

    __shared__ alignas(16) uint32_t s_pair[2 * PSEL];  // {byte_offset, A_p}
    __shared__ float s_rA[PSEL], s_rC[PSEL];
    __shared__ float s_red[2][PSEL];
    __shared__ float s_sums[2];

    if (t < PSEL) {
        int idx  = __builtin_nontemporal_load(&sel[o * PSEL + t]);
        float ww = __builtin_nontemporal_load(&w[o * PSEL + t]);
        float sw = 1.0f / (1.0f + __expf(-ww));   // resilu(w) == sigmoid(w)
        float a, c;
        if (NORM) { a = sw * g[idx]; c = sw * be[idx]; }
        else      { a = sw;          c = 0.0f; }
        s_pair[2 * t]     = (uint32_t)idx << 9;   // idx * 256 halves * 2 B
        s_pair[2 * t + 1] = __float_as_uint(a);
        if (NORM) { s_rA[t] = a; s_rC[t] = c; }
    }
    __syncthreads();

    if (NORM && t < 64) {             // wave 0 reduces sumA, sumC over 128 entries
        float va = s_rA[t] + s_rA[t + 64];
        float vc = s_rC[t] + s_rC[t + 64];
#pragma unroll
        for (int off = 32; off > 0; off >>= 1) {
            va += __shfl_down(va, off, 64);
            vc += __shfl_down(vc, off, 64);
        }
        if (t == 0) { s_sums[0] = va; s_sums[1] = vc; }
    }

    // ---- gather: 64 thin dword loads per thread, rows 2i+rp ----
    // copy select: hash decorrelated from blockIdx%8 (XCD round-robin)
    const uint2* pairs = (const uint2*)s_pair;
    const char* base = (const char*)(actT + (size_t)((o >> 3) & CMASK) * copy_stride)
                       + (uint32_t)(col * 4);
    float acc0 = 0.0f, acc1 = 0.0f;
#pragma unroll 16
    for (int i = 0; i < 64; ++i) {
        uint2 pr = pairs[2 * i + rp];               // LDS broadcast per wave
        uint32_t d = *(const uint32_t*)(base + pr.x);
        float A = __uint_as_float(pr.y);
        float2 f = __half22float2(*(const __half2*)&d);
        acc0 = fmaf(A, f.x, acc0);
        acc1 = fmaf(A, f.y, acc1);
    }

    if (t >= 128) { s_red[0][col] = acc0; s_red[1][col] = acc1; }
    __syncthreads();   // also publishes s_sums

    if (t < 128) {
        acc0 += s_red[0][col];
        acc1 += s_red[1][col];

        float z0, z1;
        float bo = bias[o];
        if (NORM) {
            float2 ms = ((const float2*)gsum)[col];
            float2 qs = ((const float2*)gsq)[col];
            float m0 = ms.x * inv_n, m1 = ms.y * inv_n;
            float q0 = qs.x * inv_n, q1 = qs.y * inv_n;
            float rs0 = rsqrtf(q0 - m0 * m0 + 1e-12f);
            float rs1 = rsqrtf(q1 - m1 * m1 + 1e-12f);
            float sA = s_sums[0], sC = s_sums[1];
            z0 = rs0 * acc0 + sC - rs0 * m0 * sA - bo;
            z1 = rs1 * acc1 + sC - rs1 * m1 * sA - bo;
        } else {
            z0 = acc0 - bo;
            z1 = acc1 - bo;
        }
        float h0 = 1.0f / (1.0f + __expf(-z0));
        float h1 = 1.0f / (1.0f + __expf(-z1));

        if (FINAL) {
            float* out = (float*)outp;
            int grp = o >> 4;
            atomicAdd(&out[(2 * col) * 256 + grp], h0);
            atomicAdd(&out[(2 * col + 1) * 256 + grp], h1);
        } else {
            __half2 hv = __floats2half2_rn(h0, h1);
            __half* ob = (__half*)outp + (size_t)o * BATCH + 2 * col;
            *(__half2*)ob = hv;                       // copy 0
            *(__half2*)(ob + H_ELEMS) = hv;           // copy 1
        }
    }
}

// ---------------------------------------------------------------------------
extern "C" void kernel_launch(void* const* d_in, const int* in_sizes, int n_in,
                              void* d_out, int out_size, void* d_ws, size_t ws_size,
                              hipStream_t stream) {
    const float* x    = (const float*)d_in[0];
    const int*   sel1 = (const int*)d_in[1];
    const float* w1   = (const float*)d_in[2];
    const float* b1   = (const float*)d_in[3];
    const float* g1   = (const float*)d_in[4];
    const float* be1  = (const float*)d_in[5];
    const int*   sel2 = (const int*)d_in[6];
    const float* w2   = (const float*)d_in[7];
    const float* b2   = (const float*)d_in[8];
    const float* g2   = (const float*)d_in[9];
    const float* be2  = (const float*)d_in[10];
    const int*   sel3 = (const int*)d_in[11];
    const float* w3   = (const float*)d_in[12];
    const float* b3   = (const float*)d_in[13];
    float* out = (float*)d_out;

    // workspace layout (fp16 activations, replicated tables)
    char* ws = (char*)d_ws;
    __half* xT  = (__half*)(ws);                              // 4 copies: 6,553,600 B
    __half* h1T = (__half*)(ws + 4 * (size_t)XT_ELEMS * 2);   // 2 copies: 8,388,608 B
    __half* h2T = (__half*)(ws + 4 * (size_t)XT_ELEMS * 2 + 2 * (size_t)H_ELEMS * 2);
    float* stats = (float*)(ws + 4 * (size_t)XT_ELEMS * 2 + 4 * (size_t)H_ELEMS * 2);
    float* gs1 = stats;
    float* gq1 = stats + 256;
    float* gs2 = stats + 512;
    float* gq2 = stats + 768;

    // transpose (4 xT copies) + init(out, stats) fused
    transpose_kernel<<<dim3(IN_DIM / 32, BATCH / 32), dim3(32, 8), 0, stream>>>(
        x, xT, out, stats);

    // Layer 1: x -> h1 (no input norm); 4-way copy hash
    popcnt_kernel<false, false, 3><<<O1_DIM, 256, 0, stream>>>(
        xT, XT_ELEMS, sel1, w1, b1, nullptr, nullptr, nullptr, nullptr, 0.0f, h1T);

    // stats of h1 for layernorm 1 (reads copy 0)
    stats_kernel<<<256, 256, 0, stream>>>(h1T, gs1, gq1, O1_DIM / 256);

    // Layer 2: layernorm(h1) folded in; 2-way copy hash
    popcnt_kernel<true, false, 1><<<O1_DIM, 256, 0, stream>>>(
        h1T, H_ELEMS, sel2, w2, b2, g1, be1, gs1, gq1, 1.0f / (float)O1_DIM, h2T);

    // stats of h2 for layernorm 2 (reads copy 0)
    stats_kernel<<<256, 256, 0, stream>>>(h2T, gs2, gq2, O1_DIM / 256);

    // Layer 3: layernorm(h2) folded in, final group-sum via atomics into out
    popcnt_kernel<true, true, 1><<<O3_DIM, 256, 0, stream>>>(
        h2T, H_ELEMS, sel3, w3, b3, g2, be2, gs2, gq2, 1.0f / (float)O1_DIM, out);
}

// Round 8
// 235.438 us; speedup vs baseline: 1.0834x; 1.0834x over previous
//
#include <hip/hip_runtime.h>
#include <hip/hip_fp16.h>
#include <stdint.h>

// Problem constants (from reference setup_inputs)
#define BATCH 256
#define PSEL  128
#define IN_DIM 3200
#define O1_DIM 8192
#define O3_DIM 4096

// ---------------------------------------------------------------------------
// transpose x [256, 3200] fp32 -> xT [3200, 256] fp16
// Fused: out = -8.0 (final bias; atomics accumulate on top) and
// stats accumulators (4 x 256 floats) = 0.
// ---------------------------------------------------------------------------
__global__ __launch_bounds__(256) void transpose_kernel(const float* __restrict__ x,
                                                        __half* __restrict__ xT,
                                                        float* __restrict__ out,
                                                        float* __restrict__ stats) {
    int tx = threadIdx.x;       // 32
    int ty = threadIdx.y;       // 8
    int tid = ty * 32 + tx;
    int gid = blockIdx.y * gridDim.x + blockIdx.x;   // 0..799
    if (gid < 256) out[gid * 256 + tid] = -8.0f;
    else if (gid < 260) stats[(gid - 256) * 256 + tid] = 0.0f;

    __shared__ float tile[32][33];
    int i0 = blockIdx.x * 32;   // input-dim tile (3200/32 = 100)
    int b0 = blockIdx.y * 32;   // batch tile    (256/32 = 8)
#pragma unroll
    for (int k = 0; k < 4; ++k)
        tile[ty + k * 8][tx] = x[(size_t)(b0 + ty + k * 8) * IN_DIM + i0 + tx];
    __syncthreads();
#pragma unroll
    for (int k = 0; k < 4; ++k)
        xT[(size_t)(i0 + ty + k * 8) * BATCH + b0 + tx] =
            __float2half(tile[tx][ty + k * 8]);
}

// ---------------------------------------------------------------------------
// stats: per-batch-column sum and sum-of-squares of hT [N, 256] (fp16 in, fp32 acc)
// grid = 256 blocks, each handles N/256 contiguous rows; coalesced reads.
// ---------------------------------------------------------------------------
__global__ __launch_bounds__(256) void stats_kernel(const __half* __restrict__ hT,
                                                    float* __restrict__ gsum,
                                                    float* __restrict__ gsq,
                                                    int rows_per_block) {
    int t = threadIdx.x;
    const __half* p = hT + (size_t)blockIdx.x * rows_per_block * BATCH + t;
    float s = 0.0f, q = 0.0f;
    for (int r = 0; r < rows_per_block; ++r) {
        float v = __half2float(p[(size_t)r * BATCH]);
        s += v;
        q = fmaf(v, v, q);
    }
    atomicAdd(&gsum[t], s);
    atomicAdd(&gsq[t], q);
}

// ---------------------------------------------------------------------------
// popcnt layer (R5 structure + explicit MLP batching): one block (256 thr)
// per output o. Thread t: batch-dword col = t&127, row-parity rp = t>>7;
// 64 thin dword loads per thread, issued in explicit batches of 8 into a
// register array so 8 loads are in flight per wave (defeats the compiler's
// register-minimizing serialization that capped every prior round at
// ~1 outstanding load/wave = 1 line per ~150 cy per wave).
// Pairs stored parity-major: s_pairP[rp][i] = {byte_off, A} for row 2i+rp,
// so a thread's batch of 8 is contiguous in LDS (broadcast ds_reads).
// Layernorm of the INPUT folded algebraically:
//   sum_p w_p*((v-mu)*rs*g_p + be_p) = rs*acc + sumC - rs*mu*sumA
// FINAL: atomicAdd sigmoid into out[b*256 + o/16] (pre-init'd to -8).
// ---------------------------------------------------------------------------
template <bool NORM, bool FINAL>
__global__ __launch_bounds__(256) void popcnt_kernel(
    const __half* __restrict__ actT,  // [Nin, 256] fp16, rows = 512 B
    const int* __restrict__ sel,      // [Nout, 128]
    const float* __restrict__ w,      // [Nout, 128]
    const float* __restrict__ bias,   // [Nout]
    const float* __restrict__ g,      // [Nin]  (NORM only)
    const float* __restrict__ be,     // [Nin]  (NORM only)
    const float* __restrict__ gsum,   // [256]  (NORM only)
    const float* __restrict__ gsq,    // [256]  (NORM only)
    float inv_n,                      // 1/Nin  (NORM only)
    void* __restrict__ outp)          // fp16 [Nout,256] or final fp32 [256,256]
{
    const int o   = blockIdx.x;
    const int t   = threadIdx.x;      // 0..255
    const int col = t & 127;          // batch dword
    const int rp  = t >> 7;           // row parity

    __shared__ alignas(16) uint2 s_pairP[2][64];   // parity-major {byte_off, A}
    __shared__ float s_rA[PSEL], s_rC[PSEL];
    __shared__ float s_red[2][PSEL];
    __shared__ float s_sums[2];

    if (t < PSEL) {
        int idx  = __builtin_nontemporal_load(&sel[o * PSEL + t]);
        float ww = __builtin_nontemporal_load(&w[o * PSEL + t]);
        float sw = 1.0f / (1.0f + __expf(-ww));   // resilu(w) == sigmoid(w)
        float a, c;
        if (NORM) { a = sw * g[idx]; c = sw * be[idx]; }
        else      { a = sw;          c = 0.0f; }
        uint2 pe;
        pe.x = (uint32_t)idx << 9;                // idx * 256 halves * 2 B
        pe.y = __float_as_uint(a);
        s_pairP[t & 1][t >> 1] = pe;              // row t = 2*(t>>1) + (t&1)
        if (NORM) { s_rA[t] = a; s_rC[t] = c; }
    }
    __syncthreads();

    if (NORM && t < 64) {             // wave 0 reduces sumA, sumC over 128 entries
        float va = s_rA[t] + s_rA[t + 64];
        float vc = s_rC[t] + s_rC[t + 64];
#pragma unroll
        for (int off = 32; off > 0; off >>= 1) {
            va += __shfl_down(va, off, 64);
            vc += __shfl_down(vc, off, 64);
        }
        if (t == 0) { s_sums[0] = va; s_sums[1] = vc; }
    }

    // ---- gather: 64 thin dword loads, explicit batches of 8 in flight ----
    const uint2* pairs = s_pairP[rp];             // 64 contiguous entries
    const char* base = (const char*)actT + (uint32_t)(col * 4);
    float acc0 = 0.0f, acc1 = 0.0f;
#pragma unroll 2
    for (int i0 = 0; i0 < 64; i0 += 8) {
        uint2 pb[8];
#pragma unroll
        for (int j = 0; j < 8; ++j) pb[j] = pairs[i0 + j];   // broadcast ds_read
        uint32_t d[8];
#pragma unroll
        for (int j = 0; j < 8; ++j)
            d[j] = *(const uint32_t*)(base + pb[j].x);       // 8 loads in flight
#pragma unroll
        for (int j = 0; j < 8; ++j) {
            float2 f = __half22float2(*(const __half2*)&d[j]);
            float A = __uint_as_float(pb[j].y);
            acc0 = fmaf(A, f.x, acc0);
            acc1 = fmaf(A, f.y, acc1);
        }
    }

    if (t >= 128) { s_red[0][col] = acc0; s_red[1][col] = acc1; }
    __syncthreads();   // also publishes s_sums

    if (t < 128) {
        acc0 += s_red[0][col];
        acc1 += s_red[1][col];

        float z0, z1;
        float bo = bias[o];
        if (NORM) {
            float2 ms = ((const float2*)gsum)[col];
            float2 qs = ((const float2*)gsq)[col];
            float m0 = ms.x * inv_n, m1 = ms.y * inv_n;
            float q0 = qs.x * inv_n, q1 = qs.y * inv_n;
            float rs0 = rsqrtf(q0 - m0 * m0 + 1e-12f);
            float rs1 = rsqrtf(q1 - m1 * m1 + 1e-12f);
            float sA = s_sums[0], sC = s_sums[1];
            z0 = rs0 * acc0 + sC - rs0 * m0 * sA - bo;
            z1 = rs1 * acc1 + sC - rs1 * m1 * sA - bo;
        } else {
            z0 = acc0 - bo;
            z1 = acc1 - bo;
        }
        float h0 = 1.0f / (1.0f + __expf(-z0));
        float h1 = 1.0f / (1.0f + __expf(-z1));

        if (FINAL) {
            float* out = (float*)outp;
            int grp = o >> 4;
            atomicAdd(&out[(2 * col) * 256 + grp], h0);
            atomicAdd(&out[(2 * col + 1) * 256 + grp], h1);
        } else {
            __half2 hv = __floats2half2_rn(h0, h1);
            *(__half2*)((__half*)outp + (size_t)o * BATCH + 2 * col) = hv;
        }
    }
}

// ---------------------------------------------------------------------------
extern "C" void kernel_launch(void* const* d_in, const int* in_sizes, int n_in,
                              void* d_out, int out_size, void* d_ws, size_t ws_size,
                              hipStream_t stream) {
    const float* x    = (const float*)d_in[0];
    const int*   sel1 = (const int*)d_in[1];
    const float* w1   = (const float*)d_in[2];
    const float* b1   = (const float*)d_in[3];
    const float* g1   = (const float*)d_in[4];
    const float* be1  = (const float*)d_in[5];
    const int*   sel2 = (const int*)d_in[6];
    const float* w2   = (const float*)d_in[7];
    const float* b2   = (const float*)d_in[8];
    const float* g2   = (const float*)d_in[9];
    const float* be2  = (const float*)d_in[10];
    const int*   sel3 = (const int*)d_in[11];
    const float* w3   = (const float*)d_in[12];
    const float* b3   = (const float*)d_in[13];
    float* out = (float*)d_out;

    // workspace layout (fp16 activations, single copy)
    char* ws = (char*)d_ws;
    __half* xT  = (__half*)(ws);                          // 3200*256*2 = 1,638,400
    __half* h1T = (__half*)(ws + 1638400);                // 8192*256*2 = 4,194,304
    __half* h2T = (__half*)(ws + 1638400 + 4194304);      // 4,194,304
    float* stats = (float*)(ws + 1638400 + 2 * 4194304);  // 4 * 256 floats
    float* gs1 = stats;
    float* gq1 = stats + 256;
    float* gs2 = stats + 512;
    float* gq2 = stats + 768;

    // transpose + init(out, stats) fused
    transpose_kernel<<<dim3(IN_DIM / 32, BATCH / 32), dim3(32, 8), 0, stream>>>(
        x, xT, out, stats);

    // Layer 1: x -> h1 (no input norm)
    popcnt_kernel<false, false><<<O1_DIM, 256, 0, stream>>>(
        xT, sel1, w1, b1, nullptr, nullptr, nullptr, nullptr, 0.0f, h1T);

    // stats of h1 for layernorm 1
    stats_kernel<<<256, 256, 0, stream>>>(h1T, gs1, gq1, O1_DIM / 256);

    // Layer 2: layernorm(h1) folded in
    popcnt_kernel<true, false><<<O1_DIM, 256, 0, stream>>>(
        h1T, sel2, w2, b2, g1, be1, gs1, gq1, 1.0f / (float)O1_DIM, h2T);

    // stats of h2 for layernorm 2
    stats_kernel<<<256, 256, 0, stream>>>(h2T, gs2, gq2, O1_DIM / 256);

    // Layer 3: layernorm(h2) folded in, final group-sum via atomics into out
    popcnt_kernel<true, true><<<O3_DIM, 256, 0, stream>>>(
        h2T, sel3, w3, b3, g2, be2, gs2, gq2, 1.0f / (float)O1_DIM, out);
}